// Round 8
// baseline (751.057 us; speedup 1.0000x reference)
//
#include <hip/hip_runtime.h>
#include <hip/hip_bf16.h>

// 5-layer GCN: widths 128 -> 128/64/32/16/8, N=100000 nodes, E=1600000 edges.
// R7: aggr v3 — each block LDS-stages its contiguous CSR index range
//     (coalesced nt loads; fallback to global if >LDSE), gather loop unrolled
//     x8 off LDS indices; nt STORES for aggr output and GEMM g output so the
//     L2-resident gather slice isn't evicted by dirty write data.
// R6: index prefetch (superseded by LDS staging); regular csr_src loads.
// R3: XCD-range-partitioned CSR build (no partial-line write amplification).
// R2: blocked g layout [f/8][N][8], slice-per-XCD L2-resident aggregation.
// R1: register-blocked fp32 GEMM (4x4 micro-tile, K-chunked LDS staging).

#define SCAN_B 1024
#define LDSE 6144   // staged edge indices per block (24 KB); P(block>6144)≈0 for Poisson(16)*128

typedef float floatx4 __attribute__((ext_vector_type(4)));

// ---------------- ranged degree histogram ----------------
__global__ __launch_bounds__(256) void k_count_r(const int* __restrict__ dst,
                                                 int* __restrict__ deg, int E, int N) {
    const int r  = blockIdx.x % 8;
    const int lo = (int)((long long)r * N / 8);
    const int hi = (int)((long long)(r + 1) * N / 8);
    const int nb = gridDim.x / 8;
    const int jb = blockIdx.x / 8;
    const int stride = nb * 256;
    for (int e = jb * 256 + threadIdx.x; e < E; e += stride) {
        int d = __builtin_nontemporal_load(&dst[e]);
        if (d >= lo && d < hi) atomicAdd(&deg[d], 1);
    }
}

// ---------------- exclusive scan (3 kernels) ----------------
__global__ void k_scan_block(const int* __restrict__ deg, int* __restrict__ out,
                             int* __restrict__ sums, int n) {
    __shared__ int tmp[SCAN_B];
    int i = blockIdx.x * SCAN_B + threadIdx.x;
    int v = (i < n) ? deg[i] : 0;
    tmp[threadIdx.x] = v;
    __syncthreads();
    for (int off = 1; off < SCAN_B; off <<= 1) {
        int t = (threadIdx.x >= off) ? tmp[threadIdx.x - off] : 0;
        __syncthreads();
        tmp[threadIdx.x] += t;
        __syncthreads();
    }
    if (i < n) out[i] = tmp[threadIdx.x] - v;   // exclusive within block
    if (threadIdx.x == SCAN_B - 1) sums[blockIdx.x] = tmp[threadIdx.x];
}

__global__ void k_scan_sums(int* __restrict__ sums, int nb) {
    __shared__ int tmp[128];
    int v = (threadIdx.x < nb) ? sums[threadIdx.x] : 0;
    tmp[threadIdx.x] = v;
    __syncthreads();
    for (int off = 1; off < 128; off <<= 1) {
        int t = (threadIdx.x >= off) ? tmp[threadIdx.x - off] : 0;
        __syncthreads();
        tmp[threadIdx.x] += t;
        __syncthreads();
    }
    if (threadIdx.x < nb) sums[threadIdx.x] = tmp[threadIdx.x] - v;  // exclusive
}

__global__ void k_finalize(int* __restrict__ offsets, const int* __restrict__ sums,
                           const int* __restrict__ deg, int* __restrict__ cursor,
                           float* __restrict__ dinv, int n, int E) {
    int i = blockIdx.x * blockDim.x + threadIdx.x;
    if (i < n) {
        int off = offsets[i] + sums[i / SCAN_B];
        offsets[i] = off;
        cursor[i]  = off;
        dinv[i]    = rsqrtf((float)(deg[i] + 1));   // +1 self loop
    }
    if (i == 0) offsets[n] = E;
}

// ---------------- ranged CSR bucket fill ----------------
__global__ __launch_bounds__(256) void k_fill_r(const int* __restrict__ src,
                                                const int* __restrict__ dst,
                                                int* __restrict__ cursor,
                                                int* __restrict__ csr_src, int E, int N) {
    const int r  = blockIdx.x % 8;
    const int lo = (int)((long long)r * N / 8);
    const int hi = (int)((long long)(r + 1) * N / 8);
    const int nb = gridDim.x / 8;
    const int jb = blockIdx.x / 8;
    const int stride = nb * 256;
    for (int e = jb * 256 + threadIdx.x; e < E; e += stride) {
        int d = __builtin_nontemporal_load(&dst[e]);
        if (d >= lo && d < hi) {
            int pos = atomicAdd(&cursor[d], 1);
            csr_src[pos] = __builtin_nontemporal_load(&src[e]);
        }
    }
}

// ---------------- register-blocked GEMM ----------------
// g_b[fo/8][n][8] = dinv[n] * sum_k x[n,k] * W[k,fo]   (blocked output, nt store)
// BIN: input x is blocked [fi/8][n][8]; else row-major [n][FIN].
template <int FIN, int FOUT, bool BIN>
__global__ __launch_bounds__(256) void k_gemm(const float* __restrict__ x,
                                              const float* __restrict__ W,
                                              const float* __restrict__ dinv,
                                              float* __restrict__ g, int n) {
    constexpr int NFG = FOUT / 4;
    constexpr int M   = 4 * (256 / NFG);
    constexpr int KC  = (FIN < 32) ? FIN : 32;
    constexpr int MP  = M + 4;
    __shared__ float Wl[KC * FOUT];
    __shared__ float xt[KC * MP];

    const int tid      = threadIdx.x;
    const int fo_group = tid % NFG;
    const int m_group  = tid / NFG;
    const int m0       = blockIdx.x * M;
    const floatx4* x4  = reinterpret_cast<const floatx4*>(x);

    float acc[4][4];
#pragma unroll
    for (int i = 0; i < 4; ++i)
#pragma unroll
        for (int j = 0; j < 4; ++j) acc[i][j] = 0.f;

    for (int kc0 = 0; kc0 < FIN; kc0 += KC) {
        __syncthreads();
        for (int i = tid; i < KC * FOUT; i += 256)
            Wl[i] = W[(kc0 + i / FOUT) * FOUT + (i % FOUT)];
        constexpr int SLOTS = KC / 4;           // float4 slots per node per chunk
        for (int s = tid; s < M * SLOTS; s += 256) {
            int ml    = s / SLOTS;
            int slot  = s % SLOTS;
            int gslot = kc0 / 4 + slot;
            int gn    = m0 + ml;
            floatx4 v = (floatx4)(0.f);
            if (gn < n) {
                size_t idx = BIN ? (((size_t)(gslot >> 1) * n + gn) * 2 + (gslot & 1))
                                 : ((size_t)gn * (FIN / 4) + gslot);
                v = __builtin_nontemporal_load(&x4[idx]);
            }
            xt[(slot * 4 + 0) * MP + ml] = v.x;
            xt[(slot * 4 + 1) * MP + ml] = v.y;
            xt[(slot * 4 + 2) * MP + ml] = v.z;
            xt[(slot * 4 + 3) * MP + ml] = v.w;
        }
        __syncthreads();
#pragma unroll
        for (int k = 0; k < KC; ++k) {
            float4 xv = *reinterpret_cast<const float4*>(&xt[k * MP + m_group * 4]);
            float4 wv = *reinterpret_cast<const float4*>(&Wl[k * FOUT + fo_group * 4]);
            const float xs[4] = {xv.x, xv.y, xv.z, xv.w};
            const float ws[4] = {wv.x, wv.y, wv.z, wv.w};
#pragma unroll
            for (int i = 0; i < 4; ++i)
#pragma unroll
                for (int j = 0; j < 4; ++j) acc[i][j] += xs[i] * ws[j];
        }
    }

    floatx4* g4 = reinterpret_cast<floatx4*>(g);
#pragma unroll
    for (int i = 0; i < 4; ++i) {
        int gn = m0 + m_group * 4 + i;
        if (gn < n) {
            float d = dinv[gn];
            floatx4 o;
            o.x = acc[i][0] * d; o.y = acc[i][1] * d;
            o.z = acc[i][2] * d; o.w = acc[i][3] * d;
            __builtin_nontemporal_store(o, &g4[((size_t)(fo_group >> 1) * n + gn) * 2 + (fo_group & 1)]);
        }
    }
}

// ---------------- sliced CSR aggregation + bias + relu (v3) ----------------
// One slice = 8 features = 3.2 MB -> per-XCD L2 resident (slice=blockIdx%nsl).
// Block = 128 nodes; its CSR index range [offsets[node0],offsets[node0+128])
// is CONTIGUOUS -> staged into LDS with coalesced nt loads. Gather loop
// unrolled x8 off LDS indices (no global index latency in the chain).
// Output written with nt stores (no reuse; keeps gather slice in L2).
__global__ __launch_bounds__(256) void k_aggr_s(const float4* __restrict__ gb,
                                                const int* __restrict__ offsets,
                                                const int* __restrict__ csr_src,
                                                const float* __restrict__ dinv,
                                                const float* __restrict__ bias,
                                                float4* __restrict__ outb,
                                                int n, int nsl, int slice_base) {
    __shared__ int eidx[LDSE];
    const int sl     = blockIdx.x % nsl;
    const int nb     = blockIdx.x / nsl;
    const int slice  = slice_base + sl;
    const int node0  = nb * 128;
    const int nodeHi = (node0 + 128 < n) ? node0 + 128 : n;
    const int node   = node0 + (threadIdx.x >> 1);
    const int h      = threadIdx.x & 1;

    const int eS = offsets[node0];
    const int eE = offsets[nodeHi];
    const int C  = eE - eS;
    const bool useLds = (C <= LDSE);
    if (useLds) {
        for (int i = threadIdx.x; i < C; i += 256)
            eidx[i] = __builtin_nontemporal_load(&csr_src[eS + i]);
    }
    __syncthreads();
    if (node >= n) return;

    const float4* gs = gb + (size_t)slice * n * 2;
    float4 a0 = gs[node * 2 + h];                 // self-loop term
    float4 a1 = make_float4(0.f, 0.f, 0.f, 0.f);
    float4 a2 = a1, a3 = a1;

    const int e0 = offsets[node];
    const int e1 = offsets[node + 1];
    const int m  = e1 - e0;
    int i = 0;
    if (useLds) {
        const int le = e0 - eS;
        for (; i + 8 <= m; i += 8) {
            int s0 = eidx[le + i + 0], s1 = eidx[le + i + 1];
            int s2 = eidx[le + i + 2], s3 = eidx[le + i + 3];
            int s4 = eidx[le + i + 4], s5 = eidx[le + i + 5];
            int s6 = eidx[le + i + 6], s7 = eidx[le + i + 7];
            float4 v0 = gs[s0 * 2 + h], v1 = gs[s1 * 2 + h];
            float4 v2 = gs[s2 * 2 + h], v3 = gs[s3 * 2 + h];
            float4 v4 = gs[s4 * 2 + h], v5 = gs[s5 * 2 + h];
            float4 v6 = gs[s6 * 2 + h], v7 = gs[s7 * 2 + h];
            a0.x += v0.x; a0.y += v0.y; a0.z += v0.z; a0.w += v0.w;
            a1.x += v1.x; a1.y += v1.y; a1.z += v1.z; a1.w += v1.w;
            a2.x += v2.x; a2.y += v2.y; a2.z += v2.z; a2.w += v2.w;
            a3.x += v3.x; a3.y += v3.y; a3.z += v3.z; a3.w += v3.w;
            a0.x += v4.x; a0.y += v4.y; a0.z += v4.z; a0.w += v4.w;
            a1.x += v5.x; a1.y += v5.y; a1.z += v5.z; a1.w += v5.w;
            a2.x += v6.x; a2.y += v6.y; a2.z += v6.z; a2.w += v6.w;
            a3.x += v7.x; a3.y += v7.y; a3.z += v7.z; a3.w += v7.w;
        }
        for (; i + 4 <= m; i += 4) {
            int s0 = eidx[le + i + 0], s1 = eidx[le + i + 1];
            int s2 = eidx[le + i + 2], s3 = eidx[le + i + 3];
            float4 v0 = gs[s0 * 2 + h], v1 = gs[s1 * 2 + h];
            float4 v2 = gs[s2 * 2 + h], v3 = gs[s3 * 2 + h];
            a0.x += v0.x; a0.y += v0.y; a0.z += v0.z; a0.w += v0.w;
            a1.x += v1.x; a1.y += v1.y; a1.z += v1.z; a1.w += v1.w;
            a2.x += v2.x; a2.y += v2.y; a2.z += v2.z; a2.w += v2.w;
            a3.x += v3.x; a3.y += v3.y; a3.z += v3.z; a3.w += v3.w;
        }
        for (; i < m; ++i) {
            float4 v = gs[eidx[le + i] * 2 + h];
            a0.x += v.x; a0.y += v.y; a0.z += v.z; a0.w += v.w;
        }
    } else {
        for (; i + 4 <= m; i += 4) {
            int s0 = csr_src[e0 + i + 0], s1 = csr_src[e0 + i + 1];
            int s2 = csr_src[e0 + i + 2], s3 = csr_src[e0 + i + 3];
            float4 v0 = gs[s0 * 2 + h], v1 = gs[s1 * 2 + h];
            float4 v2 = gs[s2 * 2 + h], v3 = gs[s3 * 2 + h];
            a0.x += v0.x; a0.y += v0.y; a0.z += v0.z; a0.w += v0.w;
            a1.x += v1.x; a1.y += v1.y; a1.z += v1.z; a1.w += v1.w;
            a2.x += v2.x; a2.y += v2.y; a2.z += v2.z; a2.w += v2.w;
            a3.x += v3.x; a3.y += v3.y; a3.z += v3.z; a3.w += v3.w;
        }
        for (; i < m; ++i) {
            float4 v = gs[csr_src[e0 + i] * 2 + h];
            a0.x += v.x; a0.y += v.y; a0.z += v.z; a0.w += v.w;
        }
    }
    a0.x += a1.x + a2.x + a3.x;
    a0.y += a1.y + a2.y + a3.y;
    a0.z += a1.z + a2.z + a3.z;
    a0.w += a1.w + a2.w + a3.w;

    const float d = dinv[node];
    const float* bf = bias + slice * 8 + h * 4;
    floatx4 r;
    r.x = fmaxf(d * a0.x + bf[0], 0.f);
    r.y = fmaxf(d * a0.y + bf[1], 0.f);
    r.z = fmaxf(d * a0.z + bf[2], 0.f);
    r.w = fmaxf(d * a0.w + bf[3], 0.f);
    floatx4* ob = reinterpret_cast<floatx4*>(outb);
    __builtin_nontemporal_store(r, &ob[((size_t)slice * n + node) * 2 + h]);
}

extern "C" void kernel_launch(void* const* d_in, const int* in_sizes, int n_in,
                              void* d_out, int out_size, void* d_ws, size_t ws_size,
                              hipStream_t stream) {
    const int N = in_sizes[0] / 128;
    const int E = in_sizes[1] / 2;

    const float* x   = (const float*)d_in[0];
    const int*   ei  = (const int*)d_in[1];
    const int*   src = ei;
    const int*   dst = ei + E;
    const float* W1 = (const float*)d_in[2],  *b1 = (const float*)d_in[3];
    const float* W2 = (const float*)d_in[4],  *b2 = (const float*)d_in[5];
    const float* W3 = (const float*)d_in[6],  *b3 = (const float*)d_in[7];
    const float* W4 = (const float*)d_in[8],  *b4 = (const float*)d_in[9];
    const float* W5 = (const float*)d_in[10], *b5 = (const float*)d_in[11];
    float* out = (float*)d_out;

    size_t off = 0;
    auto alloc = [&](size_t bytes) {
        void* p = (char*)d_ws + off;
        off += (bytes + 255) & ~(size_t)255;
        return p;
    };
    int*   deg     = (int*)alloc((size_t)N * 4);
    int*   offsets = (int*)alloc((size_t)(N + 1) * 4);
    int*   cursor  = (int*)alloc((size_t)N * 4);
    int*   sums    = (int*)alloc(128 * 4);
    float* dinv    = (float*)alloc((size_t)N * 4);
    int*   csr_src = (int*)alloc((size_t)E * 4);
    float* g       = (float*)alloc((size_t)N * 128 * 4);
    float* xbuf    = (float*)alloc((size_t)N * 128 * 4);

    (void)hipMemsetAsync(deg, 0, (size_t)N * 4, stream);

    const int TB = 256;
    int nb = (N + SCAN_B - 1) / SCAN_B;
    int nodeBlk = (N + 127) / 128;   // aggr: 128 nodes per block
    const int RG = 2048;             // ranged kernels: 256 blocks per dst-range

    k_count_r<<<RG, TB, 0, stream>>>(dst, deg, E, N);
    k_scan_block<<<nb, SCAN_B, 0, stream>>>(deg, offsets, sums, N);
    k_scan_sums<<<1, 128, 0, stream>>>(sums, nb);
    k_finalize<<<(N + TB - 1) / TB, TB, 0, stream>>>(offsets, sums, deg, cursor, dinv, N, E);
    k_fill_r<<<RG, TB, 0, stream>>>(src, dst, cursor, csr_src, E, N);

    const float4* g4  = (const float4*)g;
    float4*       xb4 = (float4*)xbuf;

    // Layer 1: 128 -> 128  (16 slices: 2 launches of 8 for XCD affinity)
    k_gemm<128, 128, false><<<(N + 31) / 32, TB, 0, stream>>>(x, W1, dinv, g, N);
    k_aggr_s<<<nodeBlk * 8, TB, 0, stream>>>(g4, offsets, csr_src, dinv, b1, xb4, N, 8, 0);
    k_aggr_s<<<nodeBlk * 8, TB, 0, stream>>>(g4, offsets, csr_src, dinv, b1, xb4, N, 8, 8);
    // Layer 2: 128 -> 64  (8 slices)
    k_gemm<128, 64, true><<<(N + 63) / 64, TB, 0, stream>>>(xbuf, W2, dinv, g, N);
    k_aggr_s<<<nodeBlk * 8, TB, 0, stream>>>(g4, offsets, csr_src, dinv, b2, xb4, N, 8, 0);
    // Layer 3: 64 -> 32  (4 slices)
    k_gemm<64, 32, true><<<(N + 127) / 128, TB, 0, stream>>>(xbuf, W3, dinv, g, N);
    k_aggr_s<<<nodeBlk * 4, TB, 0, stream>>>(g4, offsets, csr_src, dinv, b3, xb4, N, 4, 0);
    // Layer 4: 32 -> 16  (2 slices)
    k_gemm<32, 16, true><<<(N + 255) / 256, TB, 0, stream>>>(xbuf, W4, dinv, g, N);
    k_aggr_s<<<nodeBlk * 2, TB, 0, stream>>>(g4, offsets, csr_src, dinv, b4, xb4, N, 2, 0);
    // Layer 5: 16 -> 8  (1 slice; blocked F=8 == row-major -> write d_out)
    k_gemm<16, 8, true><<<(N + 511) / 512, TB, 0, stream>>>(xbuf, W5, dinv, g, N);
    k_aggr_s<<<nodeBlk * 1, TB, 0, stream>>>(g4, offsets, csr_src, dinv, b5, (float4*)out, N, 1, 0);
}

// Round 9
// 720.717 us; speedup vs baseline: 1.0421x; 1.0421x over previous
//
#include <hip/hip_runtime.h>
#include <hip/hip_bf16.h>

// 5-layer GCN: widths 128 -> 128/64/32/16/8, N=100000 nodes, E=1600000 edges.
// R8: REVERT gemm's nt g-store (R7 regression: nt bypassed L2 write-combining
//     of the 32B half-line stores -> 2x HBM write amplification, 109 MB for a
//     51 MB array, gemm 45->89 us). Regular float4 store keeps g L2-resident
//     for the following aggr. KEEP R7's aggr wins: LDS-staged CSR indices +
//     nt aggr output store.
// R3: XCD-range-partitioned CSR build (no partial-line write amplification).
// R2: blocked g layout [f/8][N][8], slice-per-XCD L2-resident aggregation.
// R1: register-blocked fp32 GEMM (4x4 micro-tile, K-chunked LDS staging).

#define SCAN_B 1024
#define LDSE 6144   // staged edge indices per block (24 KB)

typedef float floatx4 __attribute__((ext_vector_type(4)));

// ---------------- ranged degree histogram ----------------
__global__ __launch_bounds__(256) void k_count_r(const int* __restrict__ dst,
                                                 int* __restrict__ deg, int E, int N) {
    const int r  = blockIdx.x % 8;
    const int lo = (int)((long long)r * N / 8);
    const int hi = (int)((long long)(r + 1) * N / 8);
    const int nb = gridDim.x / 8;
    const int jb = blockIdx.x / 8;
    const int stride = nb * 256;
    for (int e = jb * 256 + threadIdx.x; e < E; e += stride) {
        int d = __builtin_nontemporal_load(&dst[e]);
        if (d >= lo && d < hi) atomicAdd(&deg[d], 1);
    }
}

// ---------------- exclusive scan (3 kernels) ----------------
__global__ void k_scan_block(const int* __restrict__ deg, int* __restrict__ out,
                             int* __restrict__ sums, int n) {
    __shared__ int tmp[SCAN_B];
    int i = blockIdx.x * SCAN_B + threadIdx.x;
    int v = (i < n) ? deg[i] : 0;
    tmp[threadIdx.x] = v;
    __syncthreads();
    for (int off = 1; off < SCAN_B; off <<= 1) {
        int t = (threadIdx.x >= off) ? tmp[threadIdx.x - off] : 0;
        __syncthreads();
        tmp[threadIdx.x] += t;
        __syncthreads();
    }
    if (i < n) out[i] = tmp[threadIdx.x] - v;   // exclusive within block
    if (threadIdx.x == SCAN_B - 1) sums[blockIdx.x] = tmp[threadIdx.x];
}

__global__ void k_scan_sums(int* __restrict__ sums, int nb) {
    __shared__ int tmp[128];
    int v = (threadIdx.x < nb) ? sums[threadIdx.x] : 0;
    tmp[threadIdx.x] = v;
    __syncthreads();
    for (int off = 1; off < 128; off <<= 1) {
        int t = (threadIdx.x >= off) ? tmp[threadIdx.x - off] : 0;
        __syncthreads();
        tmp[threadIdx.x] += t;
        __syncthreads();
    }
    if (threadIdx.x < nb) sums[threadIdx.x] = tmp[threadIdx.x] - v;  // exclusive
}

__global__ void k_finalize(int* __restrict__ offsets, const int* __restrict__ sums,
                           const int* __restrict__ deg, int* __restrict__ cursor,
                           float* __restrict__ dinv, int n, int E) {
    int i = blockIdx.x * blockDim.x + threadIdx.x;
    if (i < n) {
        int off = offsets[i] + sums[i / SCAN_B];
        offsets[i] = off;
        cursor[i]  = off;
        dinv[i]    = rsqrtf((float)(deg[i] + 1));   // +1 self loop
    }
    if (i == 0) offsets[n] = E;
}

// ---------------- ranged CSR bucket fill ----------------
__global__ __launch_bounds__(256) void k_fill_r(const int* __restrict__ src,
                                                const int* __restrict__ dst,
                                                int* __restrict__ cursor,
                                                int* __restrict__ csr_src, int E, int N) {
    const int r  = blockIdx.x % 8;
    const int lo = (int)((long long)r * N / 8);
    const int hi = (int)((long long)(r + 1) * N / 8);
    const int nb = gridDim.x / 8;
    const int jb = blockIdx.x / 8;
    const int stride = nb * 256;
    for (int e = jb * 256 + threadIdx.x; e < E; e += stride) {
        int d = __builtin_nontemporal_load(&dst[e]);
        if (d >= lo && d < hi) {
            int pos = atomicAdd(&cursor[d], 1);
            csr_src[pos] = __builtin_nontemporal_load(&src[e]);
        }
    }
}

// ---------------- register-blocked GEMM ----------------
// g_b[fo/8][n][8] = dinv[n] * sum_k x[n,k] * W[k,fo]   (blocked output)
// BIN: input x is blocked [fi/8][n][8]; else row-major [n][FIN].
// g store is a REGULAR store: L2 write-combining assembles full lines and the
// following aggr reads g from L2 (nt store here cost 2x HBM writes — R7).
template <int FIN, int FOUT, bool BIN>
__global__ __launch_bounds__(256) void k_gemm(const float* __restrict__ x,
                                              const float* __restrict__ W,
                                              const float* __restrict__ dinv,
                                              float* __restrict__ g, int n) {
    constexpr int NFG = FOUT / 4;
    constexpr int M   = 4 * (256 / NFG);
    constexpr int KC  = (FIN < 32) ? FIN : 32;
    constexpr int MP  = M + 4;
    __shared__ float Wl[KC * FOUT];
    __shared__ float xt[KC * MP];

    const int tid      = threadIdx.x;
    const int fo_group = tid % NFG;
    const int m_group  = tid / NFG;
    const int m0       = blockIdx.x * M;
    const floatx4* x4  = reinterpret_cast<const floatx4*>(x);

    float acc[4][4];
#pragma unroll
    for (int i = 0; i < 4; ++i)
#pragma unroll
        for (int j = 0; j < 4; ++j) acc[i][j] = 0.f;

    for (int kc0 = 0; kc0 < FIN; kc0 += KC) {
        __syncthreads();
        for (int i = tid; i < KC * FOUT; i += 256)
            Wl[i] = W[(kc0 + i / FOUT) * FOUT + (i % FOUT)];
        constexpr int SLOTS = KC / 4;           // float4 slots per node per chunk
        for (int s = tid; s < M * SLOTS; s += 256) {
            int ml    = s / SLOTS;
            int slot  = s % SLOTS;
            int gslot = kc0 / 4 + slot;
            int gn    = m0 + ml;
            floatx4 v = (floatx4)(0.f);
            if (gn < n) {
                size_t idx = BIN ? (((size_t)(gslot >> 1) * n + gn) * 2 + (gslot & 1))
                                 : ((size_t)gn * (FIN / 4) + gslot);
                v = __builtin_nontemporal_load(&x4[idx]);
            }
            xt[(slot * 4 + 0) * MP + ml] = v.x;
            xt[(slot * 4 + 1) * MP + ml] = v.y;
            xt[(slot * 4 + 2) * MP + ml] = v.z;
            xt[(slot * 4 + 3) * MP + ml] = v.w;
        }
        __syncthreads();
#pragma unroll
        for (int k = 0; k < KC; ++k) {
            float4 xv = *reinterpret_cast<const float4*>(&xt[k * MP + m_group * 4]);
            float4 wv = *reinterpret_cast<const float4*>(&Wl[k * FOUT + fo_group * 4]);
            const float xs[4] = {xv.x, xv.y, xv.z, xv.w};
            const float ws[4] = {wv.x, wv.y, wv.z, wv.w};
#pragma unroll
            for (int i = 0; i < 4; ++i)
#pragma unroll
                for (int j = 0; j < 4; ++j) acc[i][j] += xs[i] * ws[j];
        }
    }

    float4* g4 = reinterpret_cast<float4*>(g);
#pragma unroll
    for (int i = 0; i < 4; ++i) {
        int gn = m0 + m_group * 4 + i;
        if (gn < n) {
            float d = dinv[gn];
            float4 o = make_float4(acc[i][0] * d, acc[i][1] * d, acc[i][2] * d, acc[i][3] * d);
            g4[((size_t)(fo_group >> 1) * n + gn) * 2 + (fo_group & 1)] = o;
        }
    }
}

// ---------------- sliced CSR aggregation + bias + relu (v3) ----------------
// One slice = 8 features = 3.2 MB -> per-XCD L2 resident (slice=blockIdx%nsl).
// Block = 128 nodes; its CSR index range [offsets[node0],offsets[node0+128])
// is CONTIGUOUS -> staged into LDS with coalesced nt loads. Gather loop
// unrolled x8 off LDS indices (no global index latency in the chain).
// Output written with nt stores (no reuse; keeps gather slice in L2).
__global__ __launch_bounds__(256) void k_aggr_s(const float4* __restrict__ gb,
                                                const int* __restrict__ offsets,
                                                const int* __restrict__ csr_src,
                                                const float* __restrict__ dinv,
                                                const float* __restrict__ bias,
                                                float4* __restrict__ outb,
                                                int n, int nsl, int slice_base) {
    __shared__ int eidx[LDSE];
    const int sl     = blockIdx.x % nsl;
    const int nb     = blockIdx.x / nsl;
    const int slice  = slice_base + sl;
    const int node0  = nb * 128;
    const int nodeHi = (node0 + 128 < n) ? node0 + 128 : n;
    const int node   = node0 + (threadIdx.x >> 1);
    const int h      = threadIdx.x & 1;

    const int eS = offsets[node0];
    const int eE = offsets[nodeHi];
    const int C  = eE - eS;
    const bool useLds = (C <= LDSE);
    if (useLds) {
        for (int i = threadIdx.x; i < C; i += 256)
            eidx[i] = __builtin_nontemporal_load(&csr_src[eS + i]);
    }
    __syncthreads();
    if (node >= n) return;

    const float4* gs = gb + (size_t)slice * n * 2;
    float4 a0 = gs[node * 2 + h];                 // self-loop term
    float4 a1 = make_float4(0.f, 0.f, 0.f, 0.f);
    float4 a2 = a1, a3 = a1;

    const int e0 = offsets[node];
    const int e1 = offsets[node + 1];
    const int m  = e1 - e0;
    int i = 0;
    if (useLds) {
        const int le = e0 - eS;
        for (; i + 8 <= m; i += 8) {
            int s0 = eidx[le + i + 0], s1 = eidx[le + i + 1];
            int s2 = eidx[le + i + 2], s3 = eidx[le + i + 3];
            int s4 = eidx[le + i + 4], s5 = eidx[le + i + 5];
            int s6 = eidx[le + i + 6], s7 = eidx[le + i + 7];
            float4 v0 = gs[s0 * 2 + h], v1 = gs[s1 * 2 + h];
            float4 v2 = gs[s2 * 2 + h], v3 = gs[s3 * 2 + h];
            float4 v4 = gs[s4 * 2 + h], v5 = gs[s5 * 2 + h];
            float4 v6 = gs[s6 * 2 + h], v7 = gs[s7 * 2 + h];
            a0.x += v0.x; a0.y += v0.y; a0.z += v0.z; a0.w += v0.w;
            a1.x += v1.x; a1.y += v1.y; a1.z += v1.z; a1.w += v1.w;
            a2.x += v2.x; a2.y += v2.y; a2.z += v2.z; a2.w += v2.w;
            a3.x += v3.x; a3.y += v3.y; a3.z += v3.z; a3.w += v3.w;
            a0.x += v4.x; a0.y += v4.y; a0.z += v4.z; a0.w += v4.w;
            a1.x += v5.x; a1.y += v5.y; a1.z += v5.z; a1.w += v5.w;
            a2.x += v6.x; a2.y += v6.y; a2.z += v6.z; a2.w += v6.w;
            a3.x += v7.x; a3.y += v7.y; a3.z += v7.z; a3.w += v7.w;
        }
        for (; i + 4 <= m; i += 4) {
            int s0 = eidx[le + i + 0], s1 = eidx[le + i + 1];
            int s2 = eidx[le + i + 2], s3 = eidx[le + i + 3];
            float4 v0 = gs[s0 * 2 + h], v1 = gs[s1 * 2 + h];
            float4 v2 = gs[s2 * 2 + h], v3 = gs[s3 * 2 + h];
            a0.x += v0.x; a0.y += v0.y; a0.z += v0.z; a0.w += v0.w;
            a1.x += v1.x; a1.y += v1.y; a1.z += v1.z; a1.w += v1.w;
            a2.x += v2.x; a2.y += v2.y; a2.z += v2.z; a2.w += v2.w;
            a3.x += v3.x; a3.y += v3.y; a3.z += v3.z; a3.w += v3.w;
        }
        for (; i < m; ++i) {
            float4 v = gs[eidx[le + i] * 2 + h];
            a0.x += v.x; a0.y += v.y; a0.z += v.z; a0.w += v.w;
        }
    } else {
        for (; i + 4 <= m; i += 4) {
            int s0 = csr_src[e0 + i + 0], s1 = csr_src[e0 + i + 1];
            int s2 = csr_src[e0 + i + 2], s3 = csr_src[e0 + i + 3];
            float4 v0 = gs[s0 * 2 + h], v1 = gs[s1 * 2 + h];
            float4 v2 = gs[s2 * 2 + h], v3 = gs[s3 * 2 + h];
            a0.x += v0.x; a0.y += v0.y; a0.z += v0.z; a0.w += v0.w;
            a1.x += v1.x; a1.y += v1.y; a1.z += v1.z; a1.w += v1.w;
            a2.x += v2.x; a2.y += v2.y; a2.z += v2.z; a2.w += v2.w;
            a3.x += v3.x; a3.y += v3.y; a3.z += v3.z; a3.w += v3.w;
        }
        for (; i < m; ++i) {
            float4 v = gs[csr_src[e0 + i] * 2 + h];
            a0.x += v.x; a0.y += v.y; a0.z += v.z; a0.w += v.w;
        }
    }
    a0.x += a1.x + a2.x + a3.x;
    a0.y += a1.y + a2.y + a3.y;
    a0.z += a1.z + a2.z + a3.z;
    a0.w += a1.w + a2.w + a3.w;

    const float d = dinv[node];
    const float* bf = bias + slice * 8 + h * 4;
    floatx4 r;
    r.x = fmaxf(d * a0.x + bf[0], 0.f);
    r.y = fmaxf(d * a0.y + bf[1], 0.f);
    r.z = fmaxf(d * a0.z + bf[2], 0.f);
    r.w = fmaxf(d * a0.w + bf[3], 0.f);
    floatx4* ob = reinterpret_cast<floatx4*>(outb);
    __builtin_nontemporal_store(r, &ob[((size_t)slice * n + node) * 2 + h]);
}

extern "C" void kernel_launch(void* const* d_in, const int* in_sizes, int n_in,
                              void* d_out, int out_size, void* d_ws, size_t ws_size,
                              hipStream_t stream) {
    const int N = in_sizes[0] / 128;
    const int E = in_sizes[1] / 2;

    const float* x   = (const float*)d_in[0];
    const int*   ei  = (const int*)d_in[1];
    const int*   src = ei;
    const int*   dst = ei + E;
    const float* W1 = (const float*)d_in[2],  *b1 = (const float*)d_in[3];
    const float* W2 = (const float*)d_in[4],  *b2 = (const float*)d_in[5];
    const float* W3 = (const float*)d_in[6],  *b3 = (const float*)d_in[7];
    const float* W4 = (const float*)d_in[8],  *b4 = (const float*)d_in[9];
    const float* W5 = (const float*)d_in[10], *b5 = (const float*)d_in[11];
    float* out = (float*)d_out;

    size_t off = 0;
    auto alloc = [&](size_t bytes) {
        void* p = (char*)d_ws + off;
        off += (bytes + 255) & ~(size_t)255;
        return p;
    };
    int*   deg     = (int*)alloc((size_t)N * 4);
    int*   offsets = (int*)alloc((size_t)(N + 1) * 4);
    int*   cursor  = (int*)alloc((size_t)N * 4);
    int*   sums    = (int*)alloc(128 * 4);
    float* dinv    = (float*)alloc((size_t)N * 4);
    int*   csr_src = (int*)alloc((size_t)E * 4);
    float* g       = (float*)alloc((size_t)N * 128 * 4);
    float* xbuf    = (float*)alloc((size_t)N * 128 * 4);

    (void)hipMemsetAsync(deg, 0, (size_t)N * 4, stream);

    const int TB = 256;
    int nb = (N + SCAN_B - 1) / SCAN_B;
    int nodeBlk = (N + 127) / 128;   // aggr: 128 nodes per block
    const int RG = 2048;             // ranged kernels: 256 blocks per dst-range

    k_count_r<<<RG, TB, 0, stream>>>(dst, deg, E, N);
    k_scan_block<<<nb, SCAN_B, 0, stream>>>(deg, offsets, sums, N);
    k_scan_sums<<<1, 128, 0, stream>>>(sums, nb);
    k_finalize<<<(N + TB - 1) / TB, TB, 0, stream>>>(offsets, sums, deg, cursor, dinv, N, E);
    k_fill_r<<<RG, TB, 0, stream>>>(src, dst, cursor, csr_src, E, N);

    const float4* g4  = (const float4*)g;
    float4*       xb4 = (float4*)xbuf;

    // Layer 1: 128 -> 128  (16 slices: 2 launches of 8 for XCD affinity)
    k_gemm<128, 128, false><<<(N + 31) / 32, TB, 0, stream>>>(x, W1, dinv, g, N);
    k_aggr_s<<<nodeBlk * 8, TB, 0, stream>>>(g4, offsets, csr_src, dinv, b1, xb4, N, 8, 0);
    k_aggr_s<<<nodeBlk * 8, TB, 0, stream>>>(g4, offsets, csr_src, dinv, b1, xb4, N, 8, 8);
    // Layer 2: 128 -> 64  (8 slices)
    k_gemm<128, 64, true><<<(N + 63) / 64, TB, 0, stream>>>(xbuf, W2, dinv, g, N);
    k_aggr_s<<<nodeBlk * 8, TB, 0, stream>>>(g4, offsets, csr_src, dinv, b2, xb4, N, 8, 0);
    // Layer 3: 64 -> 32  (4 slices)
    k_gemm<64, 32, true><<<(N + 127) / 128, TB, 0, stream>>>(xbuf, W3, dinv, g, N);
    k_aggr_s<<<nodeBlk * 4, TB, 0, stream>>>(g4, offsets, csr_src, dinv, b3, xb4, N, 4, 0);
    // Layer 4: 32 -> 16  (2 slices)
    k_gemm<32, 16, true><<<(N + 255) / 256, TB, 0, stream>>>(xbuf, W4, dinv, g, N);
    k_aggr_s<<<nodeBlk * 2, TB, 0, stream>>>(g4, offsets, csr_src, dinv, b4, xb4, N, 2, 0);
    // Layer 5: 16 -> 8  (1 slice; blocked F=8 == row-major -> write d_out)
    k_gemm<16, 8, true><<<(N + 511) / 512, TB, 0, stream>>>(xbuf, W5, dinv, g, N);
    k_aggr_s<<<nodeBlk * 1, TB, 0, stream>>>(g4, offsets, csr_src, dinv, b5, (float4*)out, N, 1, 0);
}

// Round 10
// 717.471 us; speedup vs baseline: 1.0468x; 1.0045x over previous
//
#include <hip/hip_runtime.h>
#include <hip/hip_bf16.h>

// 5-layer GCN: widths 128 -> 128/64/32/16/8, N=100000 nodes, E=1600000 edges.
// R9: occupancy fix for aggr — LDSE 6144->4096 (24->16 KB) lifts blocks/CU
//     from 6 to the 8-block wave cap (~100% occ): the kernel is L2-gather-
//     LATENCY-bound (FETCH only 42 MB, HBM 10%), so resident-wave count is
//     the direct throughput knob. Offsets/self-loop loads hoisted above the
//     LDS staging loop. Binomial(E,128/N): mean 2048, sigma 45 -> P(>4096)=0;
//     global fallback kept for safety.
// R8: regular g store (L2 write-combining + keeps g L2-resident for aggr).
// R7: aggr LDS-staged CSR indices + nt aggr output store.
// R3: XCD-range-partitioned CSR build (no partial-line write amplification).
// R2: blocked g layout [f/8][N][8], slice-per-XCD L2-resident aggregation.
// R1: register-blocked fp32 GEMM (4x4 micro-tile, K-chunked LDS staging).

#define SCAN_B 1024
#define LDSE 4096   // staged edge indices per block (16 KB) -> 8 blocks/CU

typedef float floatx4 __attribute__((ext_vector_type(4)));

// ---------------- ranged degree histogram ----------------
__global__ __launch_bounds__(256) void k_count_r(const int* __restrict__ dst,
                                                 int* __restrict__ deg, int E, int N) {
    const int r  = blockIdx.x % 8;
    const int lo = (int)((long long)r * N / 8);
    const int hi = (int)((long long)(r + 1) * N / 8);
    const int nb = gridDim.x / 8;
    const int jb = blockIdx.x / 8;
    const int stride = nb * 256;
    for (int e = jb * 256 + threadIdx.x; e < E; e += stride) {
        int d = __builtin_nontemporal_load(&dst[e]);
        if (d >= lo && d < hi) atomicAdd(&deg[d], 1);
    }
}

// ---------------- exclusive scan (3 kernels) ----------------
__global__ void k_scan_block(const int* __restrict__ deg, int* __restrict__ out,
                             int* __restrict__ sums, int n) {
    __shared__ int tmp[SCAN_B];
    int i = blockIdx.x * SCAN_B + threadIdx.x;
    int v = (i < n) ? deg[i] : 0;
    tmp[threadIdx.x] = v;
    __syncthreads();
    for (int off = 1; off < SCAN_B; off <<= 1) {
        int t = (threadIdx.x >= off) ? tmp[threadIdx.x - off] : 0;
        __syncthreads();
        tmp[threadIdx.x] += t;
        __syncthreads();
    }
    if (i < n) out[i] = tmp[threadIdx.x] - v;   // exclusive within block
    if (threadIdx.x == SCAN_B - 1) sums[blockIdx.x] = tmp[threadIdx.x];
}

__global__ void k_scan_sums(int* __restrict__ sums, int nb) {
    __shared__ int tmp[128];
    int v = (threadIdx.x < nb) ? sums[threadIdx.x] : 0;
    tmp[threadIdx.x] = v;
    __syncthreads();
    for (int off = 1; off < 128; off <<= 1) {
        int t = (threadIdx.x >= off) ? tmp[threadIdx.x - off] : 0;
        __syncthreads();
        tmp[threadIdx.x] += t;
        __syncthreads();
    }
    if (threadIdx.x < nb) sums[threadIdx.x] = tmp[threadIdx.x] - v;  // exclusive
}

__global__ void k_finalize(int* __restrict__ offsets, const int* __restrict__ sums,
                           const int* __restrict__ deg, int* __restrict__ cursor,
                           float* __restrict__ dinv, int n, int E) {
    int i = blockIdx.x * blockDim.x + threadIdx.x;
    if (i < n) {
        int off = offsets[i] + sums[i / SCAN_B];
        offsets[i] = off;
        cursor[i]  = off;
        dinv[i]    = rsqrtf((float)(deg[i] + 1));   // +1 self loop
    }
    if (i == 0) offsets[n] = E;
}

// ---------------- ranged CSR bucket fill ----------------
__global__ __launch_bounds__(256) void k_fill_r(const int* __restrict__ src,
                                                const int* __restrict__ dst,
                                                int* __restrict__ cursor,
                                                int* __restrict__ csr_src, int E, int N) {
    const int r  = blockIdx.x % 8;
    const int lo = (int)((long long)r * N / 8);
    const int hi = (int)((long long)(r + 1) * N / 8);
    const int nb = gridDim.x / 8;
    const int jb = blockIdx.x / 8;
    const int stride = nb * 256;
    for (int e = jb * 256 + threadIdx.x; e < E; e += stride) {
        int d = __builtin_nontemporal_load(&dst[e]);
        if (d >= lo && d < hi) {
            int pos = atomicAdd(&cursor[d], 1);
            csr_src[pos] = __builtin_nontemporal_load(&src[e]);
        }
    }
}

// ---------------- register-blocked GEMM ----------------
// g_b[fo/8][n][8] = dinv[n] * sum_k x[n,k] * W[k,fo]   (blocked output)
// BIN: input x is blocked [fi/8][n][8]; else row-major [n][FIN].
template <int FIN, int FOUT, bool BIN>
__global__ __launch_bounds__(256) void k_gemm(const float* __restrict__ x,
                                              const float* __restrict__ W,
                                              const float* __restrict__ dinv,
                                              float* __restrict__ g, int n) {
    constexpr int NFG = FOUT / 4;
    constexpr int M   = 4 * (256 / NFG);
    constexpr int KC  = (FIN < 32) ? FIN : 32;
    constexpr int MP  = M + 4;
    __shared__ float Wl[KC * FOUT];
    __shared__ float xt[KC * MP];

    const int tid      = threadIdx.x;
    const int fo_group = tid % NFG;
    const int m_group  = tid / NFG;
    const int m0       = blockIdx.x * M;
    const floatx4* x4  = reinterpret_cast<const floatx4*>(x);

    float acc[4][4];
#pragma unroll
    for (int i = 0; i < 4; ++i)
#pragma unroll
        for (int j = 0; j < 4; ++j) acc[i][j] = 0.f;

    for (int kc0 = 0; kc0 < FIN; kc0 += KC) {
        __syncthreads();
        for (int i = tid; i < KC * FOUT; i += 256)
            Wl[i] = W[(kc0 + i / FOUT) * FOUT + (i % FOUT)];
        constexpr int SLOTS = KC / 4;           // float4 slots per node per chunk
        for (int s = tid; s < M * SLOTS; s += 256) {
            int ml    = s / SLOTS;
            int slot  = s % SLOTS;
            int gslot = kc0 / 4 + slot;
            int gn    = m0 + ml;
            floatx4 v = (floatx4)(0.f);
            if (gn < n) {
                size_t idx = BIN ? (((size_t)(gslot >> 1) * n + gn) * 2 + (gslot & 1))
                                 : ((size_t)gn * (FIN / 4) + gslot);
                v = __builtin_nontemporal_load(&x4[idx]);
            }
            xt[(slot * 4 + 0) * MP + ml] = v.x;
            xt[(slot * 4 + 1) * MP + ml] = v.y;
            xt[(slot * 4 + 2) * MP + ml] = v.z;
            xt[(slot * 4 + 3) * MP + ml] = v.w;
        }
        __syncthreads();
#pragma unroll
        for (int k = 0; k < KC; ++k) {
            float4 xv = *reinterpret_cast<const float4*>(&xt[k * MP + m_group * 4]);
            float4 wv = *reinterpret_cast<const float4*>(&Wl[k * FOUT + fo_group * 4]);
            const float xs[4] = {xv.x, xv.y, xv.z, xv.w};
            const float ws[4] = {wv.x, wv.y, wv.z, wv.w};
#pragma unroll
            for (int i = 0; i < 4; ++i)
#pragma unroll
                for (int j = 0; j < 4; ++j) acc[i][j] += xs[i] * ws[j];
        }
    }

    float4* g4 = reinterpret_cast<float4*>(g);
#pragma unroll
    for (int i = 0; i < 4; ++i) {
        int gn = m0 + m_group * 4 + i;
        if (gn < n) {
            float d = dinv[gn];
            float4 o = make_float4(acc[i][0] * d, acc[i][1] * d, acc[i][2] * d, acc[i][3] * d);
            g4[((size_t)(fo_group >> 1) * n + gn) * 2 + (fo_group & 1)] = o;
        }
    }
}

// ---------------- sliced CSR aggregation + bias + relu (v4) ----------------
// One slice = 8 features = 3.2 MB -> per-XCD L2 resident (slice=blockIdx%nsl).
// Block = 128 nodes; its contiguous CSR index range staged into LDS (16 KB ->
// 8 blocks/CU, full wave occupancy: the kernel is L2-latency-bound so
// resident-wave count is the throughput knob). Gather loop unrolled x8.
// Output written with nt stores (no reuse; keeps gather slice in L2).
__global__ __launch_bounds__(256) void k_aggr_s(const float4* __restrict__ gb,
                                                const int* __restrict__ offsets,
                                                const int* __restrict__ csr_src,
                                                const float* __restrict__ dinv,
                                                const float* __restrict__ bias,
                                                float4* __restrict__ outb,
                                                int n, int nsl, int slice_base) {
    __shared__ int eidx[LDSE];
    const int sl     = blockIdx.x % nsl;
    const int nb     = blockIdx.x / nsl;
    const int slice  = slice_base + sl;
    const int node0  = nb * 128;
    const int nodeHi = (node0 + 128 < n) ? node0 + 128 : n;
    const int node   = node0 + (threadIdx.x >> 1);
    const int h      = threadIdx.x & 1;

    const int eS = offsets[node0];
    const int eE = offsets[nodeHi];
    const int C  = eE - eS;
    const bool useLds = (C <= LDSE);

    // hoist per-node state loads to overlap with LDS staging
    const bool alive = (node < n);
    int e0 = 0, e1 = 0;
    float dnode = 0.f;
    const float4* gs = gb + (size_t)slice * n * 2;
    float4 a0 = make_float4(0.f, 0.f, 0.f, 0.f);
    if (alive) {
        e0 = offsets[node];
        e1 = offsets[node + 1];
        dnode = dinv[node];
        a0 = gs[node * 2 + h];                    // self-loop term
    }

    if (useLds) {
        for (int i = threadIdx.x; i < C; i += 256)
            eidx[i] = __builtin_nontemporal_load(&csr_src[eS + i]);
    }
    __syncthreads();
    if (!alive) return;

    float4 a1 = make_float4(0.f, 0.f, 0.f, 0.f);
    float4 a2 = a1, a3 = a1;

    const int m = e1 - e0;
    int i = 0;
    if (useLds) {
        const int le = e0 - eS;
        for (; i + 8 <= m; i += 8) {
            int s0 = eidx[le + i + 0], s1 = eidx[le + i + 1];
            int s2 = eidx[le + i + 2], s3 = eidx[le + i + 3];
            int s4 = eidx[le + i + 4], s5 = eidx[le + i + 5];
            int s6 = eidx[le + i + 6], s7 = eidx[le + i + 7];
            float4 v0 = gs[s0 * 2 + h], v1 = gs[s1 * 2 + h];
            float4 v2 = gs[s2 * 2 + h], v3 = gs[s3 * 2 + h];
            float4 v4 = gs[s4 * 2 + h], v5 = gs[s5 * 2 + h];
            float4 v6 = gs[s6 * 2 + h], v7 = gs[s7 * 2 + h];
            a0.x += v0.x; a0.y += v0.y; a0.z += v0.z; a0.w += v0.w;
            a1.x += v1.x; a1.y += v1.y; a1.z += v1.z; a1.w += v1.w;
            a2.x += v2.x; a2.y += v2.y; a2.z += v2.z; a2.w += v2.w;
            a3.x += v3.x; a3.y += v3.y; a3.z += v3.z; a3.w += v3.w;
            a0.x += v4.x; a0.y += v4.y; a0.z += v4.z; a0.w += v4.w;
            a1.x += v5.x; a1.y += v5.y; a1.z += v5.z; a1.w += v5.w;
            a2.x += v6.x; a2.y += v6.y; a2.z += v6.z; a2.w += v6.w;
            a3.x += v7.x; a3.y += v7.y; a3.z += v7.z; a3.w += v7.w;
        }
        for (; i + 4 <= m; i += 4) {
            int s0 = eidx[le + i + 0], s1 = eidx[le + i + 1];
            int s2 = eidx[le + i + 2], s3 = eidx[le + i + 3];
            float4 v0 = gs[s0 * 2 + h], v1 = gs[s1 * 2 + h];
            float4 v2 = gs[s2 * 2 + h], v3 = gs[s3 * 2 + h];
            a0.x += v0.x; a0.y += v0.y; a0.z += v0.z; a0.w += v0.w;
            a1.x += v1.x; a1.y += v1.y; a1.z += v1.z; a1.w += v1.w;
            a2.x += v2.x; a2.y += v2.y; a2.z += v2.z; a2.w += v2.w;
            a3.x += v3.x; a3.y += v3.y; a3.z += v3.z; a3.w += v3.w;
        }
        for (; i < m; ++i) {
            float4 v = gs[eidx[le + i] * 2 + h];
            a0.x += v.x; a0.y += v.y; a0.z += v.z; a0.w += v.w;
        }
    } else {
        for (; i + 4 <= m; i += 4) {
            int s0 = csr_src[e0 + i + 0], s1 = csr_src[e0 + i + 1];
            int s2 = csr_src[e0 + i + 2], s3 = csr_src[e0 + i + 3];
            float4 v0 = gs[s0 * 2 + h], v1 = gs[s1 * 2 + h];
            float4 v2 = gs[s2 * 2 + h], v3 = gs[s3 * 2 + h];
            a0.x += v0.x; a0.y += v0.y; a0.z += v0.z; a0.w += v0.w;
            a1.x += v1.x; a1.y += v1.y; a1.z += v1.z; a1.w += v1.w;
            a2.x += v2.x; a2.y += v2.y; a2.z += v2.z; a2.w += v2.w;
            a3.x += v3.x; a3.y += v3.y; a3.z += v3.z; a3.w += v3.w;
        }
        for (; i < m; ++i) {
            float4 v = gs[csr_src[e0 + i] * 2 + h];
            a0.x += v.x; a0.y += v.y; a0.z += v.z; a0.w += v.w;
        }
    }
    a0.x += a1.x + a2.x + a3.x;
    a0.y += a1.y + a2.y + a3.y;
    a0.z += a1.z + a2.z + a3.z;
    a0.w += a1.w + a2.w + a3.w;

    const float* bf = bias + slice * 8 + h * 4;
    floatx4 r;
    r.x = fmaxf(dnode * a0.x + bf[0], 0.f);
    r.y = fmaxf(dnode * a0.y + bf[1], 0.f);
    r.z = fmaxf(dnode * a0.z + bf[2], 0.f);
    r.w = fmaxf(dnode * a0.w + bf[3], 0.f);
    floatx4* ob = reinterpret_cast<floatx4*>(outb);
    __builtin_nontemporal_store(r, &ob[((size_t)slice * n + node) * 2 + h]);
}

extern "C" void kernel_launch(void* const* d_in, const int* in_sizes, int n_in,
                              void* d_out, int out_size, void* d_ws, size_t ws_size,
                              hipStream_t stream) {
    const int N = in_sizes[0] / 128;
    const int E = in_sizes[1] / 2;

    const float* x   = (const float*)d_in[0];
    const int*   ei  = (const int*)d_in[1];
    const int*   src = ei;
    const int*   dst = ei + E;
    const float* W1 = (const float*)d_in[2],  *b1 = (const float*)d_in[3];
    const float* W2 = (const float*)d_in[4],  *b2 = (const float*)d_in[5];
    const float* W3 = (const float*)d_in[6],  *b3 = (const float*)d_in[7];
    const float* W4 = (const float*)d_in[8],  *b4 = (const float*)d_in[9];
    const float* W5 = (const float*)d_in[10], *b5 = (const float*)d_in[11];
    float* out = (float*)d_out;

    size_t off = 0;
    auto alloc = [&](size_t bytes) {
        void* p = (char*)d_ws + off;
        off += (bytes + 255) & ~(size_t)255;
        return p;
    };
    int*   deg     = (int*)alloc((size_t)N * 4);
    int*   offsets = (int*)alloc((size_t)(N + 1) * 4);
    int*   cursor  = (int*)alloc((size_t)N * 4);
    int*   sums    = (int*)alloc(128 * 4);
    float* dinv    = (float*)alloc((size_t)N * 4);
    int*   csr_src = (int*)alloc((size_t)E * 4);
    float* g       = (float*)alloc((size_t)N * 128 * 4);
    float* xbuf    = (float*)alloc((size_t)N * 128 * 4);

    (void)hipMemsetAsync(deg, 0, (size_t)N * 4, stream);

    const int TB = 256;
    int nb = (N + SCAN_B - 1) / SCAN_B;
    int nodeBlk = (N + 127) / 128;   // aggr: 128 nodes per block
    const int RG = 2048;             // ranged kernels: 256 blocks per dst-range

    k_count_r<<<RG, TB, 0, stream>>>(dst, deg, E, N);
    k_scan_block<<<nb, SCAN_B, 0, stream>>>(deg, offsets, sums, N);
    k_scan_sums<<<1, 128, 0, stream>>>(sums, nb);
    k_finalize<<<(N + TB - 1) / TB, TB, 0, stream>>>(offsets, sums, deg, cursor, dinv, N, E);
    k_fill_r<<<RG, TB, 0, stream>>>(src, dst, cursor, csr_src, E, N);

    const float4* g4  = (const float4*)g;
    float4*       xb4 = (float4*)xbuf;

    // Layer 1: 128 -> 128  (16 slices: 2 launches of 8 for XCD affinity)
    k_gemm<128, 128, false><<<(N + 31) / 32, TB, 0, stream>>>(x, W1, dinv, g, N);
    k_aggr_s<<<nodeBlk * 8, TB, 0, stream>>>(g4, offsets, csr_src, dinv, b1, xb4, N, 8, 0);
    k_aggr_s<<<nodeBlk * 8, TB, 0, stream>>>(g4, offsets, csr_src, dinv, b1, xb4, N, 8, 8);
    // Layer 2: 128 -> 64  (8 slices)
    k_gemm<128, 64, true><<<(N + 63) / 64, TB, 0, stream>>>(xbuf, W2, dinv, g, N);
    k_aggr_s<<<nodeBlk * 8, TB, 0, stream>>>(g4, offsets, csr_src, dinv, b2, xb4, N, 8, 0);
    // Layer 3: 64 -> 32  (4 slices)
    k_gemm<64, 32, true><<<(N + 127) / 128, TB, 0, stream>>>(xbuf, W3, dinv, g, N);
    k_aggr_s<<<nodeBlk * 4, TB, 0, stream>>>(g4, offsets, csr_src, dinv, b3, xb4, N, 4, 0);
    // Layer 4: 32 -> 16  (2 slices)
    k_gemm<32, 16, true><<<(N + 255) / 256, TB, 0, stream>>>(xbuf, W4, dinv, g, N);
    k_aggr_s<<<nodeBlk * 2, TB, 0, stream>>>(g4, offsets, csr_src, dinv, b4, xb4, N, 2, 0);
    // Layer 5: 16 -> 8  (1 slice; blocked F=8 == row-major -> write d_out)
    k_gemm<16, 8, true><<<(N + 511) / 512, TB, 0, stream>>>(xbuf, W5, dinv, g, N);
    k_aggr_s<<<nodeBlk * 1, TB, 0, stream>>>(g4, offsets, csr_src, dinv, b5, (float4*)out, N, 1, 0);
}

// Round 11
// 637.581 us; speedup vs baseline: 1.1780x; 1.1253x over previous
//
#include <hip/hip_runtime.h>
#include <hip/hip_bf16.h>

// 5-layer GCN: widths 128 -> 128/64/32/16/8, N=100000 nodes, E=1600000 edges.
// R10: L2-CHANNEL model — aggr is bound by L2 channel-cycles (64 B line fill
//      = 2 cyc @32 B/cyc/ch; 12.8M fills/dispatch ≈ 83 µs = observed). With
//      8-feat slices only 32 B of each fetched line is useful. Re-block g as
//      [f/16][N][16] (64 B/node/slice16), 4 lanes per node -> every line
//      fill fully used -> channel-cycles per layer halve. Layer 1 aggr is
//      now ONE dispatch of 8 slice16s. Layer 5 (F=8) keeps 2-lane kernel.
// R9:  16 KB LDS staging (occupancy probe -> revealed throughput ceiling).
// R8:  regular g store (L2 write-combining; g stays L2-resident for aggr).
// R7:  aggr LDS-staged CSR indices + nt aggr output store.
// R3:  XCD-range-partitioned CSR build (no partial-line write amplification).
// R1:  register-blocked fp32 GEMM (4x4 micro-tile, K-chunked LDS staging).

#define SCAN_B 1024
#define LDSE8  4096   // aggr8: staged edge indices (16 KB), 128 nodes/block
#define LDSE16 2048   // aggr16: staged edge indices (8 KB), 64 nodes/block

typedef float floatx4 __attribute__((ext_vector_type(4)));

// ---------------- ranged degree histogram ----------------
__global__ __launch_bounds__(256) void k_count_r(const int* __restrict__ dst,
                                                 int* __restrict__ deg, int E, int N) {
    const int r  = blockIdx.x % 8;
    const int lo = (int)((long long)r * N / 8);
    const int hi = (int)((long long)(r + 1) * N / 8);
    const int nb = gridDim.x / 8;
    const int jb = blockIdx.x / 8;
    const int stride = nb * 256;
    for (int e = jb * 256 + threadIdx.x; e < E; e += stride) {
        int d = __builtin_nontemporal_load(&dst[e]);
        if (d >= lo && d < hi) atomicAdd(&deg[d], 1);
    }
}

// ---------------- exclusive scan (3 kernels) ----------------
__global__ void k_scan_block(const int* __restrict__ deg, int* __restrict__ out,
                             int* __restrict__ sums, int n) {
    __shared__ int tmp[SCAN_B];
    int i = blockIdx.x * SCAN_B + threadIdx.x;
    int v = (i < n) ? deg[i] : 0;
    tmp[threadIdx.x] = v;
    __syncthreads();
    for (int off = 1; off < SCAN_B; off <<= 1) {
        int t = (threadIdx.x >= off) ? tmp[threadIdx.x - off] : 0;
        __syncthreads();
        tmp[threadIdx.x] += t;
        __syncthreads();
    }
    if (i < n) out[i] = tmp[threadIdx.x] - v;   // exclusive within block
    if (threadIdx.x == SCAN_B - 1) sums[blockIdx.x] = tmp[threadIdx.x];
}

__global__ void k_scan_sums(int* __restrict__ sums, int nb) {
    __shared__ int tmp[128];
    int v = (threadIdx.x < nb) ? sums[threadIdx.x] : 0;
    tmp[threadIdx.x] = v;
    __syncthreads();
    for (int off = 1; off < 128; off <<= 1) {
        int t = (threadIdx.x >= off) ? tmp[threadIdx.x - off] : 0;
        __syncthreads();
        tmp[threadIdx.x] += t;
        __syncthreads();
    }
    if (threadIdx.x < nb) sums[threadIdx.x] = tmp[threadIdx.x] - v;  // exclusive
}

__global__ void k_finalize(int* __restrict__ offsets, const int* __restrict__ sums,
                           const int* __restrict__ deg, int* __restrict__ cursor,
                           float* __restrict__ dinv, int n, int E) {
    int i = blockIdx.x * blockDim.x + threadIdx.x;
    if (i < n) {
        int off = offsets[i] + sums[i / SCAN_B];
        offsets[i] = off;
        cursor[i]  = off;
        dinv[i]    = rsqrtf((float)(deg[i] + 1));   // +1 self loop
    }
    if (i == 0) offsets[n] = E;
}

// ---------------- ranged CSR bucket fill ----------------
__global__ __launch_bounds__(256) void k_fill_r(const int* __restrict__ src,
                                                const int* __restrict__ dst,
                                                int* __restrict__ cursor,
                                                int* __restrict__ csr_src, int E, int N) {
    const int r  = blockIdx.x % 8;
    const int lo = (int)((long long)r * N / 8);
    const int hi = (int)((long long)(r + 1) * N / 8);
    const int nb = gridDim.x / 8;
    const int jb = blockIdx.x / 8;
    const int stride = nb * 256;
    for (int e = jb * 256 + threadIdx.x; e < E; e += stride) {
        int d = __builtin_nontemporal_load(&dst[e]);
        if (d >= lo && d < hi) {
            int pos = atomicAdd(&cursor[d], 1);
            csr_src[pos] = __builtin_nontemporal_load(&src[e]);
        }
    }
}

// ---------------- register-blocked GEMM ----------------
// Output: FOUT>=16 -> blocked16 g[fo/16][n][16]; FOUT==8 -> row-major [n][8].
// Input:  BIN -> blocked16 [fi/16][n][16]; else row-major [n][FIN].
template <int FIN, int FOUT, bool BIN>
__global__ __launch_bounds__(256) void k_gemm(const float* __restrict__ x,
                                              const float* __restrict__ W,
                                              const float* __restrict__ dinv,
                                              float* __restrict__ g, int n) {
    constexpr int NFG = FOUT / 4;
    constexpr int M   = 4 * (256 / NFG);
    constexpr int KC  = (FIN < 32) ? FIN : 32;
    constexpr int MP  = M + 4;
    __shared__ float Wl[KC * FOUT];
    __shared__ float xt[KC * MP];

    const int tid      = threadIdx.x;
    const int fo_group = tid % NFG;
    const int m_group  = tid / NFG;
    const int m0       = blockIdx.x * M;
    const floatx4* x4  = reinterpret_cast<const floatx4*>(x);

    float acc[4][4];
#pragma unroll
    for (int i = 0; i < 4; ++i)
#pragma unroll
        for (int j = 0; j < 4; ++j) acc[i][j] = 0.f;

    for (int kc0 = 0; kc0 < FIN; kc0 += KC) {
        __syncthreads();
        for (int i = tid; i < KC * FOUT; i += 256)
            Wl[i] = W[(kc0 + i / FOUT) * FOUT + (i % FOUT)];
        constexpr int SLOTS = KC / 4;           // float4 slots per node per chunk
        for (int s = tid; s < M * SLOTS; s += 256) {
            int ml    = s / SLOTS;
            int slot  = s % SLOTS;
            int gslot = kc0 / 4 + slot;
            int gn    = m0 + ml;
            floatx4 v = (floatx4)(0.f);
            if (gn < n) {
                size_t idx = BIN ? (((size_t)(gslot >> 2) * n + gn) * 4 + (gslot & 3))
                                 : ((size_t)gn * (FIN / 4) + gslot);
                v = __builtin_nontemporal_load(&x4[idx]);
            }
            xt[(slot * 4 + 0) * MP + ml] = v.x;
            xt[(slot * 4 + 1) * MP + ml] = v.y;
            xt[(slot * 4 + 2) * MP + ml] = v.z;
            xt[(slot * 4 + 3) * MP + ml] = v.w;
        }
        __syncthreads();
#pragma unroll
        for (int k = 0; k < KC; ++k) {
            float4 xv = *reinterpret_cast<const float4*>(&xt[k * MP + m_group * 4]);
            float4 wv = *reinterpret_cast<const float4*>(&Wl[k * FOUT + fo_group * 4]);
            const float xs[4] = {xv.x, xv.y, xv.z, xv.w};
            const float ws[4] = {wv.x, wv.y, wv.z, wv.w};
#pragma unroll
            for (int i = 0; i < 4; ++i)
#pragma unroll
                for (int j = 0; j < 4; ++j) acc[i][j] += xs[i] * ws[j];
        }
    }

    float4* g4 = reinterpret_cast<float4*>(g);
#pragma unroll
    for (int i = 0; i < 4; ++i) {
        int gn = m0 + m_group * 4 + i;
        if (gn < n) {
            float d = dinv[gn];
            float4 o = make_float4(acc[i][0] * d, acc[i][1] * d, acc[i][2] * d, acc[i][3] * d);
            if (FOUT >= 16)
                g4[((size_t)(fo_group >> 2) * n + gn) * 4 + (fo_group & 3)] = o;
            else
                g4[(size_t)gn * 2 + fo_group] = o;
        }
    }
}

// ---------------- 16-feature-slice CSR aggregation (layers 1-4) ----------------
// g blocked [f/16][N][16]: 64 B per node per slice16 -> 4 lanes/node read one
// full 64 B line per edge (every fetched byte useful; halves L2 channel
// cycles vs 8-feat slices). slice16 = blockIdx%nsl for XCD affinity.
// 64 nodes/block; contiguous CSR range staged in 8 KB LDS.
__global__ __launch_bounds__(256) void k_aggr16(const float4* __restrict__ gb,
                                                const int* __restrict__ offsets,
                                                const int* __restrict__ csr_src,
                                                const float* __restrict__ dinv,
                                                const float* __restrict__ bias,
                                                float4* __restrict__ outb,
                                                int n, int nsl) {
    __shared__ int eidx[LDSE16];
    const int sl     = blockIdx.x % nsl;
    const int nb     = blockIdx.x / nsl;
    const int node0  = nb * 64;
    const int nodeHi = (node0 + 64 < n) ? node0 + 64 : n;
    const int node   = node0 + (threadIdx.x >> 2);
    const int q      = threadIdx.x & 3;

    const int eS = offsets[node0];
    const int eE = offsets[nodeHi];
    const int C  = eE - eS;
    const bool useLds = (C <= LDSE16);

    const bool alive = (node < n);
    int e0 = 0, e1 = 0;
    float dnode = 0.f;
    const float4* gs = gb + (size_t)sl * n * 4;
    float4 a0 = make_float4(0.f, 0.f, 0.f, 0.f);
    if (alive) {
        e0 = offsets[node];
        e1 = offsets[node + 1];
        dnode = dinv[node];
        a0 = gs[(size_t)node * 4 + q];            // self-loop term
    }

    if (useLds) {
        for (int i = threadIdx.x; i < C; i += 256)
            eidx[i] = __builtin_nontemporal_load(&csr_src[eS + i]);
    }
    __syncthreads();
    if (!alive) return;

    float4 a1 = make_float4(0.f, 0.f, 0.f, 0.f);
    float4 a2 = a1, a3 = a1;

    const int m = e1 - e0;
    int i = 0;
    if (useLds) {
        const int le = e0 - eS;
        for (; i + 8 <= m; i += 8) {
            int s0 = eidx[le + i + 0], s1 = eidx[le + i + 1];
            int s2 = eidx[le + i + 2], s3 = eidx[le + i + 3];
            int s4 = eidx[le + i + 4], s5 = eidx[le + i + 5];
            int s6 = eidx[le + i + 6], s7 = eidx[le + i + 7];
            float4 v0 = gs[(size_t)s0 * 4 + q], v1 = gs[(size_t)s1 * 4 + q];
            float4 v2 = gs[(size_t)s2 * 4 + q], v3 = gs[(size_t)s3 * 4 + q];
            float4 v4 = gs[(size_t)s4 * 4 + q], v5 = gs[(size_t)s5 * 4 + q];
            float4 v6 = gs[(size_t)s6 * 4 + q], v7 = gs[(size_t)s7 * 4 + q];
            a0.x += v0.x; a0.y += v0.y; a0.z += v0.z; a0.w += v0.w;
            a1.x += v1.x; a1.y += v1.y; a1.z += v1.z; a1.w += v1.w;
            a2.x += v2.x; a2.y += v2.y; a2.z += v2.z; a2.w += v2.w;
            a3.x += v3.x; a3.y += v3.y; a3.z += v3.z; a3.w += v3.w;
            a0.x += v4.x; a0.y += v4.y; a0.z += v4.z; a0.w += v4.w;
            a1.x += v5.x; a1.y += v5.y; a1.z += v5.z; a1.w += v5.w;
            a2.x += v6.x; a2.y += v6.y; a2.z += v6.z; a2.w += v6.w;
            a3.x += v7.x; a3.y += v7.y; a3.z += v7.z; a3.w += v7.w;
        }
        for (; i + 4 <= m; i += 4) {
            int s0 = eidx[le + i + 0], s1 = eidx[le + i + 1];
            int s2 = eidx[le + i + 2], s3 = eidx[le + i + 3];
            float4 v0 = gs[(size_t)s0 * 4 + q], v1 = gs[(size_t)s1 * 4 + q];
            float4 v2 = gs[(size_t)s2 * 4 + q], v3 = gs[(size_t)s3 * 4 + q];
            a0.x += v0.x; a0.y += v0.y; a0.z += v0.z; a0.w += v0.w;
            a1.x += v1.x; a1.y += v1.y; a1.z += v1.z; a1.w += v1.w;
            a2.x += v2.x; a2.y += v2.y; a2.z += v2.z; a2.w += v2.w;
            a3.x += v3.x; a3.y += v3.y; a3.z += v3.z; a3.w += v3.w;
        }
        for (; i < m; ++i) {
            float4 v = gs[(size_t)eidx[le + i] * 4 + q];
            a0.x += v.x; a0.y += v.y; a0.z += v.z; a0.w += v.w;
        }
    } else {
        for (; i + 4 <= m; i += 4) {
            int s0 = csr_src[e0 + i + 0], s1 = csr_src[e0 + i + 1];
            int s2 = csr_src[e0 + i + 2], s3 = csr_src[e0 + i + 3];
            float4 v0 = gs[(size_t)s0 * 4 + q], v1 = gs[(size_t)s1 * 4 + q];
            float4 v2 = gs[(size_t)s2 * 4 + q], v3 = gs[(size_t)s3 * 4 + q];
            a0.x += v0.x; a0.y += v0.y; a0.z += v0.z; a0.w += v0.w;
            a1.x += v1.x; a1.y += v1.y; a1.z += v1.z; a1.w += v1.w;
            a2.x += v2.x; a2.y += v2.y; a2.z += v2.z; a2.w += v2.w;
            a3.x += v3.x; a3.y += v3.y; a3.z += v3.z; a3.w += v3.w;
        }
        for (; i < m; ++i) {
            float4 v = gs[(size_t)csr_src[e0 + i] * 4 + q];
            a0.x += v.x; a0.y += v.y; a0.z += v.z; a0.w += v.w;
        }
    }
    a0.x += a1.x + a2.x + a3.x;
    a0.y += a1.y + a2.y + a3.y;
    a0.z += a1.z + a2.z + a3.z;
    a0.w += a1.w + a2.w + a3.w;

    const float* bf = bias + sl * 16 + q * 4;
    floatx4 r;
    r.x = fmaxf(dnode * a0.x + bf[0], 0.f);
    r.y = fmaxf(dnode * a0.y + bf[1], 0.f);
    r.z = fmaxf(dnode * a0.z + bf[2], 0.f);
    r.w = fmaxf(dnode * a0.w + bf[3], 0.f);
    floatx4* ob = reinterpret_cast<floatx4*>(outb);
    __builtin_nontemporal_store(r, &ob[((size_t)sl * n + node) * 4 + q]);
}

// ---------------- 8-feature CSR aggregation (layer 5, writes d_out) --------
__global__ __launch_bounds__(256) void k_aggr8(const float4* __restrict__ gb,
                                               const int* __restrict__ offsets,
                                               const int* __restrict__ csr_src,
                                               const float* __restrict__ dinv,
                                               const float* __restrict__ bias,
                                               float4* __restrict__ outb, int n) {
    __shared__ int eidx[LDSE8];
    const int node0  = blockIdx.x * 128;
    const int nodeHi = (node0 + 128 < n) ? node0 + 128 : n;
    const int node   = node0 + (threadIdx.x >> 1);
    const int h      = threadIdx.x & 1;

    const int eS = offsets[node0];
    const int eE = offsets[nodeHi];
    const int C  = eE - eS;
    const bool useLds = (C <= LDSE8);

    const bool alive = (node < n);
    int e0 = 0, e1 = 0;
    float dnode = 0.f;
    float4 a0 = make_float4(0.f, 0.f, 0.f, 0.f);
    if (alive) {
        e0 = offsets[node];
        e1 = offsets[node + 1];
        dnode = dinv[node];
        a0 = gb[(size_t)node * 2 + h];            // self-loop term
    }

    if (useLds) {
        for (int i = threadIdx.x; i < C; i += 256)
            eidx[i] = __builtin_nontemporal_load(&csr_src[eS + i]);
    }
    __syncthreads();
    if (!alive) return;

    float4 a1 = make_float4(0.f, 0.f, 0.f, 0.f);
    float4 a2 = a1, a3 = a1;

    const int m = e1 - e0;
    int i = 0;
    if (useLds) {
        const int le = e0 - eS;
        for (; i + 4 <= m; i += 4) {
            int s0 = eidx[le + i + 0], s1 = eidx[le + i + 1];
            int s2 = eidx[le + i + 2], s3 = eidx[le + i + 3];
            float4 v0 = gb[(size_t)s0 * 2 + h], v1 = gb[(size_t)s1 * 2 + h];
            float4 v2 = gb[(size_t)s2 * 2 + h], v3 = gb[(size_t)s3 * 2 + h];
            a0.x += v0.x; a0.y += v0.y; a0.z += v0.z; a0.w += v0.w;
            a1.x += v1.x; a1.y += v1.y; a1.z += v1.z; a1.w += v1.w;
            a2.x += v2.x; a2.y += v2.y; a2.z += v2.z; a2.w += v2.w;
            a3.x += v3.x; a3.y += v3.y; a3.z += v3.z; a3.w += v3.w;
        }
        for (; i < m; ++i) {
            float4 v = gb[(size_t)eidx[le + i] * 2 + h];
            a0.x += v.x; a0.y += v.y; a0.z += v.z; a0.w += v.w;
        }
    } else {
        for (; i < m; ++i) {
            float4 v = gb[(size_t)csr_src[e0 + i] * 2 + h];
            a0.x += v.x; a0.y += v.y; a0.z += v.z; a0.w += v.w;
        }
    }
    a0.x += a1.x + a2.x + a3.x;
    a0.y += a1.y + a2.y + a3.y;
    a0.z += a1.z + a2.z + a3.z;
    a0.w += a1.w + a2.w + a3.w;

    const float* bf = bias + h * 4;
    floatx4 r;
    r.x = fmaxf(dnode * a0.x + bf[0], 0.f);
    r.y = fmaxf(dnode * a0.y + bf[1], 0.f);
    r.z = fmaxf(dnode * a0.z + bf[2], 0.f);
    r.w = fmaxf(dnode * a0.w + bf[3], 0.f);
    floatx4* ob = reinterpret_cast<floatx4*>(outb);
    __builtin_nontemporal_store(r, &ob[(size_t)node * 2 + h]);
}

extern "C" void kernel_launch(void* const* d_in, const int* in_sizes, int n_in,
                              void* d_out, int out_size, void* d_ws, size_t ws_size,
                              hipStream_t stream) {
    const int N = in_sizes[0] / 128;
    const int E = in_sizes[1] / 2;

    const float* x   = (const float*)d_in[0];
    const int*   ei  = (const int*)d_in[1];
    const int*   src = ei;
    const int*   dst = ei + E;
    const float* W1 = (const float*)d_in[2],  *b1 = (const float*)d_in[3];
    const float* W2 = (const float*)d_in[4],  *b2 = (const float*)d_in[5];
    const float* W3 = (const float*)d_in[6],  *b3 = (const float*)d_in[7];
    const float* W4 = (const float*)d_in[8],  *b4 = (const float*)d_in[9];
    const float* W5 = (const float*)d_in[10], *b5 = (const float*)d_in[11];
    float* out = (float*)d_out;

    size_t off = 0;
    auto alloc = [&](size_t bytes) {
        void* p = (char*)d_ws + off;
        off += (bytes + 255) & ~(size_t)255;
        return p;
    };
    int*   deg     = (int*)alloc((size_t)N * 4);
    int*   offsets = (int*)alloc((size_t)(N + 1) * 4);
    int*   cursor  = (int*)alloc((size_t)N * 4);
    int*   sums    = (int*)alloc(128 * 4);
    float* dinv    = (float*)alloc((size_t)N * 4);
    int*   csr_src = (int*)alloc((size_t)E * 4);
    float* g       = (float*)alloc((size_t)N * 128 * 4);
    float* xbuf    = (float*)alloc((size_t)N * 128 * 4);

    (void)hipMemsetAsync(deg, 0, (size_t)N * 4, stream);

    const int TB = 256;
    int nb = (N + SCAN_B - 1) / SCAN_B;
    int nb16 = (N + 63) / 64;        // aggr16: 64 nodes per block
    int nb8  = (N + 127) / 128;      // aggr8: 128 nodes per block
    const int RG = 2048;             // ranged kernels: 256 blocks per dst-range

    k_count_r<<<RG, TB, 0, stream>>>(dst, deg, E, N);
    k_scan_block<<<nb, SCAN_B, 0, stream>>>(deg, offsets, sums, N);
    k_scan_sums<<<1, 128, 0, stream>>>(sums, nb);
    k_finalize<<<(N + TB - 1) / TB, TB, 0, stream>>>(offsets, sums, deg, cursor, dinv, N, E);
    k_fill_r<<<RG, TB, 0, stream>>>(src, dst, cursor, csr_src, E, N);

    const float4* g4  = (const float4*)g;
    float4*       xb4 = (float4*)xbuf;

    // Layer 1: 128 -> 128  (8 slice16s, ONE dispatch)
    k_gemm<128, 128, false><<<(N + 31) / 32, TB, 0, stream>>>(x, W1, dinv, g, N);
    k_aggr16<<<nb16 * 8, TB, 0, stream>>>(g4, offsets, csr_src, dinv, b1, xb4, N, 8);
    // Layer 2: 128 -> 64  (4 slice16s)
    k_gemm<128, 64, true><<<(N + 63) / 64, TB, 0, stream>>>(xbuf, W2, dinv, g, N);
    k_aggr16<<<nb16 * 4, TB, 0, stream>>>(g4, offsets, csr_src, dinv, b2, xb4, N, 4);
    // Layer 3: 64 -> 32  (2 slice16s)
    k_gemm<64, 32, true><<<(N + 127) / 128, TB, 0, stream>>>(xbuf, W3, dinv, g, N);
    k_aggr16<<<nb16 * 2, TB, 0, stream>>>(g4, offsets, csr_src, dinv, b3, xb4, N, 2);
    // Layer 4: 32 -> 16  (1 slice16)
    k_gemm<32, 16, true><<<(N + 255) / 256, TB, 0, stream>>>(xbuf, W4, dinv, g, N);
    k_aggr16<<<nb16 * 1, TB, 0, stream>>>(g4, offsets, csr_src, dinv, b4, xb4, N, 1);
    // Layer 5: 16 -> 8  (row-major F=8; aggr8 writes d_out)
    k_gemm<16, 8, true><<<(N + 511) / 512, TB, 0, stream>>>(xbuf, W5, dinv, g, N);
    k_aggr8<<<nb8, TB, 0, stream>>>(g4, offsets, csr_src, dinv, b5, (float4*)out, N);
}